// Round 9
// baseline (442.104 us; speedup 1.0000x reference)
//
#include <hip/hip_runtime.h>

// GCN: 2x GraphConv(norm='both') + per-graph mean + [hg|perm] @ Wc + bc
// N=100000, E=1600000, D=H=128, P=64, C=10, G=128
// R9: XCD-sharded feature columns — features stored chunk-major (8 chunks x 16
// cols, 3.2 MB each); chunk = blockIdx%8 pins each chunk to one XCD's L2, so
// agg gathers hit L2 instead of refilling 177 MB from L3 every dispatch.

#define NUM_G 128
#define PB_EDGES 4096   // edges per partition block
#define W_BIN 128       // nodes per bin (key>>7)

typedef unsigned int uint32;
typedef short bf16x8 __attribute__((ext_vector_type(8)));
typedef float f32x4 __attribute__((ext_vector_type(4)));

__device__ __forceinline__ float bflo(uint32 u) { return __uint_as_float(u << 16); }
__device__ __forceinline__ float bfhi(uint32 u) { return __uint_as_float(u & 0xffff0000u); }
__device__ __forceinline__ uint32 f2bf_bits(float f) {  // RNE
    uint32 b = __float_as_uint(f);
    return (b + 0x7fffu + ((b >> 16) & 1u)) >> 16;
}
__device__ __forceinline__ uint32 pack2(float a, float b) {
    return f2bf_bits(a) | (f2bf_bits(b) << 16);
}

// ---- P1: per-block LDS histogram of key>>7. pipe0=dst, pipe1=src ----
__global__ __launch_bounds__(256) void p1_hist(const int* __restrict__ src,
                                               const int* __restrict__ dst, int E,
                                               int NBIN, int B, int* __restrict__ bh) {
    __shared__ int hist[1024];
    int b = blockIdx.x;
    int pipe = (b >= B) ? 1 : 0;
    int bb = pipe ? b - B : b;
    const int* key = pipe ? src : dst;
    for (int i = threadIdx.x; i < NBIN; i += 256) hist[i] = 0;
    __syncthreads();
    int base = bb * PB_EDGES;
    for (int c = threadIdx.x; c < PB_EDGES / 4; c += 256) {
        int e = base + c * 4;
        if (e + 3 < E) {
            int4 k4 = *(const int4*)(key + e);
            atomicAdd(&hist[k4.x >> 7], 1);
            atomicAdd(&hist[k4.y >> 7], 1);
            atomicAdd(&hist[k4.z >> 7], 1);
            atomicAdd(&hist[k4.w >> 7], 1);
        } else {
            for (int i = e; i < E && i < e + 4; i++) atomicAdd(&hist[key[i] >> 7], 1);
        }
    }
    __syncthreads();
    int* outp = bh + (size_t)pipe * NBIN * B;
    for (int k = threadIdx.x; k < NBIN; k += 256)
        outp[(size_t)k * B + bb] = hist[k];
}

// ---- P2a: tot[pipe][k] = sum_b bh[pipe][k][b] ----
__global__ __launch_bounds__(256) void p2a_tot(const int* __restrict__ bh, int NBIN, int B,
                                               int* __restrict__ tot) {
    __shared__ int sc[256];
    int k = blockIdx.x % NBIN, pipe = blockIdx.x / NBIN;
    const int* row = bh + (size_t)pipe * NBIN * B + (size_t)k * B;
    int acc = 0;
    for (int b = threadIdx.x; b < B; b += 256) acc += row[b];
    sc[threadIdx.x] = acc;
    __syncthreads();
    for (int o = 128; o > 0; o >>= 1) {
        if (threadIdx.x < o) sc[threadIdx.x] += sc[threadIdx.x + o];
        __syncthreads();
    }
    if (threadIdx.x == 0) tot[pipe * NBIN + k] = sc[0];
}

// ---- P2c: block (pipe,k): base = prefix(tot) inline; write bstart; scan bh over B ----
__global__ __launch_bounds__(512) void p2c_cursor(const int* __restrict__ bh,
                                                  const int* __restrict__ tot,
                                                  int NBIN, int B, int E,
                                                  int* __restrict__ bstart,
                                                  int* __restrict__ curs) {
    __shared__ int sc[512];
    int k = blockIdx.x % NBIN, pipe = blockIdx.x / NBIN;
    int i = threadIdx.x;
    int pacc = 0;
    for (int kk = i; kk < k; kk += 512) pacc += tot[pipe * NBIN + kk];
    sc[i] = pacc;
    __syncthreads();
    for (int o = 256; o > 0; o >>= 1) {
        if (i < o) sc[i] += sc[i + o];
        __syncthreads();
    }
    int base = sc[0];
    __syncthreads();
    if (i == 0) {
        bstart[pipe * (NBIN + 1) + k] = base;
        if (k == 0) bstart[pipe * (NBIN + 1) + NBIN] = E;
    }
    const int* row = bh + (size_t)pipe * NBIN * B + (size_t)k * B;
    int v = (i < B) ? row[i] : 0;
    sc[i] = v;
    __syncthreads();
    for (int o = 1; o < 512; o <<= 1) {
        int t = (i >= o) ? sc[i - o] : 0;
        __syncthreads();
        sc[i] += t;
        __syncthreads();
    }
    if (i < B)
        curs[(size_t)pipe * B * NBIN + (size_t)i * NBIN + k] = base + sc[i] - v;
}

// ---- P3: scatter edges into bin-partitioned buffers (LDS cursors) ----
__global__ __launch_bounds__(256) void p3_scatter(const int* __restrict__ src,
                                                  const int* __restrict__ dst, int E,
                                                  int NBIN, int B, const int* __restrict__ curs,
                                                  int2* __restrict__ ebuf, int* __restrict__ sbuf) {
    __shared__ int cur[1024];
    int b = blockIdx.x;
    int pipe = (b >= B) ? 1 : 0;
    int bb = pipe ? b - B : b;
    const int* crow = curs + (size_t)pipe * B * NBIN + (size_t)bb * NBIN;
    for (int i = threadIdx.x; i < NBIN; i += 256) cur[i] = crow[i];
    __syncthreads();
    int base = bb * PB_EDGES;
    if (!pipe) {
        for (int c = threadIdx.x; c < PB_EDGES / 4; c += 256) {
            int e = base + c * 4;
            if (e + 3 < E) {
                int4 s4 = *(const int4*)(src + e);
                int4 d4 = *(const int4*)(dst + e);
                int p;
                p = atomicAdd(&cur[d4.x >> 7], 1); ebuf[p] = make_int2(s4.x, d4.x);
                p = atomicAdd(&cur[d4.y >> 7], 1); ebuf[p] = make_int2(s4.y, d4.y);
                p = atomicAdd(&cur[d4.z >> 7], 1); ebuf[p] = make_int2(s4.z, d4.z);
                p = atomicAdd(&cur[d4.w >> 7], 1); ebuf[p] = make_int2(s4.w, d4.w);
            } else {
                for (int i = e; i < E && i < e + 4; i++) {
                    int s = src[i], d = dst[i];
                    int p = atomicAdd(&cur[d >> 7], 1);
                    ebuf[p] = make_int2(s, d);
                }
            }
        }
    } else {
        for (int c = threadIdx.x; c < PB_EDGES / 4; c += 256) {
            int e = base + c * 4;
            if (e + 3 < E) {
                int4 s4 = *(const int4*)(src + e);
                int p;
                p = atomicAdd(&cur[s4.x >> 7], 1); sbuf[p] = s4.x;
                p = atomicAdd(&cur[s4.y >> 7], 1); sbuf[p] = s4.y;
                p = atomicAdd(&cur[s4.z >> 7], 1); sbuf[p] = s4.z;
                p = atomicAdd(&cur[s4.w >> 7], 1); sbuf[p] = s4.w;
            } else {
                for (int i = e; i < E && i < e + 4; i++) {
                    int s = src[i];
                    int p = atomicAdd(&cur[s >> 7], 1);
                    sbuf[p] = s;
                }
            }
        }
    }
}

// ---- P4 (fused): k<NBIN: per-bin CSR; k>=NBIN: per-bin outdeg ----
__global__ __launch_bounds__(256) void p4_comb(const int2* __restrict__ ebuf,
                                               const int* __restrict__ sbuf,
                                               const int* __restrict__ bstart,
                                               int NBIN, int N, int E,
                                               int* __restrict__ indeg, int* __restrict__ coff,
                                               int* __restrict__ adj, int* __restrict__ outdeg) {
    __shared__ int hist[128];
    __shared__ int sc[128];
    __shared__ int cur[128];
    __shared__ int lsrc[4096];
    int kb = blockIdx.x;
    int tid = threadIdx.x;
    if (kb >= NBIN) {
        int k = kb - NBIN;
        const int* bstartS = bstart + (NBIN + 1);
        int s0 = bstartS[k], s1 = bstartS[k + 1];
        if (tid < 128) hist[tid] = 0;
        __syncthreads();
        for (int i = s0 + tid; i < s1; i += 256) atomicAdd(&hist[sbuf[i] & 127], 1);
        __syncthreads();
        if (tid < 128) {
            int node = k * W_BIN + tid;
            if (node < N) outdeg[node] = hist[tid];
        }
        return;
    }
    int k = kb;
    int s0 = bstart[k], s1 = bstart[k + 1];
    int M = s1 - s0;
    if (tid < 128) hist[tid] = 0;
    __syncthreads();
    for (int i = tid; i < M; i += 256) {
        int2 e = ebuf[s0 + i];
        atomicAdd(&hist[e.y & 127], 1);
    }
    __syncthreads();
    if (tid < 128) sc[tid] = hist[tid];
    __syncthreads();
    for (int o = 1; o < 128; o <<= 1) {
        int v = 0;
        if (tid < 128 && tid >= o) v = sc[tid - o];
        __syncthreads();
        if (tid < 128) sc[tid] += v;
        __syncthreads();
    }
    if (tid < 128) {
        int node = k * W_BIN + tid;
        if (node < N) {
            indeg[node] = hist[tid];
            coff[node] = s0 + sc[tid] - hist[tid];
        }
        cur[tid] = sc[tid] - hist[tid];
    }
    if (k == NBIN - 1 && tid == 0) coff[N] = E;
    __syncthreads();
    if (M <= 4096) {
        for (int i = tid; i < M; i += 256) {
            int2 e = ebuf[s0 + i];
            int p = atomicAdd(&cur[e.y & 127], 1);
            lsrc[p] = e.x;
        }
        __syncthreads();
        for (int i = tid; i < M; i += 256) adj[s0 + i] = lsrc[i];
    } else {
        for (int i = tid; i < M; i += 256) {
            int2 e = ebuf[s0 + i];
            int p = atomicAdd(&cur[e.y & 127], 1);
            adj[s0 + p] = e.x;
        }
    }
}

// ---- misc (fused): goffs boundary-detect + degree norms + Wt bf16 transpose ----
__global__ void misc_kernel(const int* __restrict__ gids,
                            const int* __restrict__ outdeg, const int* __restrict__ indeg,
                            const float* __restrict__ W1, const float* __restrict__ W2,
                            int N, int* __restrict__ goffs,
                            float* __restrict__ nrm_out, float* __restrict__ nrm_in,
                            unsigned short* __restrict__ Wt1, unsigned short* __restrict__ Wt2) {
    int i = blockIdx.x * blockDim.x + threadIdx.x;
    if (i <= N) {
        int prev = (i == 0) ? -1 : gids[i - 1];
        int cur = (i == N) ? NUM_G : gids[i];
        for (int g = prev + 1; g <= cur && g <= NUM_G; g++) goffs[g] = i;
    }
    if (i < N) {
        nrm_out[i] = rsqrtf(fmaxf((float)outdeg[i], 1.0f));
        nrm_in[i]  = rsqrtf(fmaxf((float)indeg[i], 1.0f));
    }
    if (i < 32768) {
        int sel = i >> 14;
        int idx = i & 16383;
        int k = idx >> 7, n = idx & 127;
        float v = (sel ? W2 : W1)[idx];
        (sel ? Wt2 : Wt1)[n * 128 + k] = (unsigned short)f2bf_bits(v);
    }
}

// ---- scale into CHUNKED layout: chunk c holds cols [c*16, c*16+16) of all rows ----
// block: 128 nodes of one chunk (c = blockIdx%8 -> XCD-pinned), 2 lanes/node.
__global__ __launch_bounds__(256) void scale_kernel(const float* __restrict__ h,
                                                    const float* __restrict__ nrm_out,
                                                    uint32* __restrict__ xsb, int N) {
    int c = blockIdx.x & 7;
    int node = (blockIdx.x >> 3) * 128 + (threadIdx.x >> 1);
    int half = threadIdx.x & 1;
    if (node >= N) return;
    float ns = nrm_out[node];
    const float4* hv = (const float4*)(h + (size_t)node * 128 + c * 16 + half * 8);
    float4 a = hv[0], b = hv[1];
    a.x *= ns; a.y *= ns; a.z *= ns; a.w *= ns;
    b.x *= ns; b.y *= ns; b.z *= ns; b.w *= ns;
    uint4 o;
    o.x = pack2(a.x, a.y); o.y = pack2(a.z, a.w);
    o.z = pack2(b.x, b.y); o.w = pack2(b.z, b.w);
    ((uint4*)xsb)[(size_t)c * N * 2 + (size_t)node * 2 + half] = o;
}

// ---- aggregation over CHUNKED features: gathers confined to one 3.2MB chunk ----
// (one XCD's L2). 2 lanes/node/chunk, 16B/lane, unroll-4. In/out both chunked.
__global__ __launch_bounds__(256) void agg_kernel(const uint32* __restrict__ xsb,
                                                  const int* __restrict__ adj,
                                                  const int* __restrict__ coff,
                                                  uint32* __restrict__ aggb, int N) {
    int c = blockIdx.x & 7;
    int node = (blockIdx.x >> 3) * 128 + (threadIdx.x >> 1);
    int half = threadIdx.x & 1;
    if (node >= N) return;
    int jb = coff[node], je = coff[node + 1];
    const uint4* rows = (const uint4*)xsb + (size_t)c * N * 2 + half;
    float acc[8];
#pragma unroll
    for (int i = 0; i < 8; i++) acc[i] = 0.f;
    int j = jb;
    for (; j + 3 < je; j += 4) {
        int s0 = adj[j], s1 = adj[j + 1], s2 = adj[j + 2], s3 = adj[j + 3];
        uint4 u0 = rows[(size_t)s0 * 2];
        uint4 u1 = rows[(size_t)s1 * 2];
        uint4 u2 = rows[(size_t)s2 * 2];
        uint4 u3 = rows[(size_t)s3 * 2];
        acc[0] += bflo(u0.x); acc[1] += bfhi(u0.x); acc[2] += bflo(u0.y); acc[3] += bfhi(u0.y);
        acc[4] += bflo(u0.z); acc[5] += bfhi(u0.z); acc[6] += bflo(u0.w); acc[7] += bfhi(u0.w);
        acc[0] += bflo(u1.x); acc[1] += bfhi(u1.x); acc[2] += bflo(u1.y); acc[3] += bfhi(u1.y);
        acc[4] += bflo(u1.z); acc[5] += bfhi(u1.z); acc[6] += bflo(u1.w); acc[7] += bfhi(u1.w);
        acc[0] += bflo(u2.x); acc[1] += bfhi(u2.x); acc[2] += bflo(u2.y); acc[3] += bfhi(u2.y);
        acc[4] += bflo(u2.z); acc[5] += bfhi(u2.z); acc[6] += bflo(u2.w); acc[7] += bfhi(u2.w);
        acc[0] += bflo(u3.x); acc[1] += bfhi(u3.x); acc[2] += bflo(u3.y); acc[3] += bfhi(u3.y);
        acc[4] += bflo(u3.z); acc[5] += bfhi(u3.z); acc[6] += bflo(u3.w); acc[7] += bfhi(u3.w);
    }
    for (; j < je; j++) {
        int s = adj[j];
        uint4 u = rows[(size_t)s * 2];
        acc[0] += bflo(u.x); acc[1] += bfhi(u.x); acc[2] += bflo(u.y); acc[3] += bfhi(u.y);
        acc[4] += bflo(u.z); acc[5] += bfhi(u.z); acc[6] += bflo(u.w); acc[7] += bfhi(u.w);
    }
    uint4 o;
    o.x = pack2(acc[0], acc[1]); o.y = pack2(acc[2], acc[3]);
    o.z = pack2(acc[4], acc[5]); o.w = pack2(acc[6], acc[7]);
    ((uint4*)aggb)[(size_t)c * N * 2 + (size_t)node * 2 + half] = o;
}

// ---- MFMA GEMM: A read from CHUNKED layout; out chunked (layer1) or row-major ----
// chunk of col k = k>>4: A-frag k-range kk*32+quad*8 -> chunk = kk*2+(quad>>1),
// offset (quad&1)*8. Out col c = t*16+col_l -> chunk = t, offset col_l.
template <bool OUT_CHUNKED>
__global__ __launch_bounds__(256) void gemm_mfma(const unsigned short* __restrict__ A,
                                                 const unsigned short* __restrict__ Wtg,
                                                 const float* __restrict__ bias,
                                                 const float* __restrict__ rowscale,
                                                 const float* __restrict__ postscale,
                                                 unsigned short* __restrict__ out,
                                                 int N, int do_relu) {
    __shared__ unsigned short Wl[128 * 136];
    for (int i = threadIdx.x; i < 2048; i += 256) {
        uint4 v = ((const uint4*)Wtg)[i];
        *(uint4*)&Wl[(i >> 4) * 136 + (i & 15) * 8] = v;
    }
    __syncthreads();

    const size_t CS = (size_t)N * 16;  // shorts per chunk
    int lane = threadIdx.x & 63;
    int wv = threadIdx.x >> 6;
    int col_l = lane & 15;
    int quad = lane >> 4;
    int r0w = blockIdx.x * 128 + wv * 32;
    if (r0w >= N) return;

    int arow0 = r0w + col_l;        if (arow0 >= N) arow0 = N - 1;
    int arow1 = r0w + 16 + col_l;   if (arow1 >= N) arow1 = N - 1;
    size_t lchunk = (size_t)(quad >> 1) * CS + (quad & 1) * 8;
    const unsigned short* Ar0 = A + lchunk + (size_t)arow0 * 16;
    const unsigned short* Ar1 = A + lchunk + (size_t)arow1 * 16;

    f32x4 acc[2][8];
#pragma unroll
    for (int rt = 0; rt < 2; rt++)
#pragma unroll
        for (int t = 0; t < 8; t++) {
            acc[rt][t][0] = 0.f; acc[rt][t][1] = 0.f;
            acc[rt][t][2] = 0.f; acc[rt][t][3] = 0.f;
        }

#pragma unroll
    for (int kk = 0; kk < 4; kk++) {
        bf16x8 a0 = *(const bf16x8*)(Ar0 + (size_t)kk * 2 * CS);
        bf16x8 a1 = *(const bf16x8*)(Ar1 + (size_t)kk * 2 * CS);
        const unsigned short* wb = &Wl[(size_t)col_l * 136 + kk * 32 + quad * 8];
#pragma unroll
        for (int t = 0; t < 8; t++) {
            bf16x8 b = *(const bf16x8*)(wb + (size_t)t * 16 * 136);
            acc[0][t] = __builtin_amdgcn_mfma_f32_16x16x32_bf16(a0, b, acc[0][t], 0, 0, 0);
            acc[1][t] = __builtin_amdgcn_mfma_f32_16x16x32_bf16(a1, b, acc[1][t], 0, 0, 0);
        }
    }

#pragma unroll
    for (int rt = 0; rt < 2; rt++) {
        int rbase = r0w + rt * 16;
        float s[4], p[4];
#pragma unroll
        for (int j = 0; j < 4; j++) {
            int rw = rbase + quad * 4 + j;
            bool ok = rw < N;
            s[j] = ok ? rowscale[ok ? rw : 0] : 0.f;
            p[j] = (postscale != nullptr && ok) ? postscale[rw] : 1.f;
        }
#pragma unroll
        for (int t = 0; t < 8; t++) {
            int c = t * 16 + col_l;
            float bia = bias[c];
#pragma unroll
            for (int j = 0; j < 4; j++) {
                int rw = rbase + quad * 4 + j;
                if (rw >= N) continue;
                float v = fmaf(s[j], acc[rt][t][j], bia);
                if (do_relu) v = fmaxf(v, 0.f);
                v *= p[j];
                if (OUT_CHUNKED)
                    out[(size_t)t * CS + (size_t)rw * 16 + col_l] = (unsigned short)f2bf_bits(v);
                else
                    out[(size_t)rw * 128 + c] = (unsigned short)f2bf_bits(v);
            }
        }
    }
}

// ---- fused per-graph mean + classifier head (x2 row-major bf16) ----
__global__ __launch_bounds__(1024) void mean_final(const uint32* __restrict__ x2b,
                                                   const int* __restrict__ goffs,
                                                   const float* __restrict__ perm,
                                                   const float* __restrict__ Wc,
                                                   const float* __restrict__ bc,
                                                   float* __restrict__ out) {
    __shared__ float red[16][128];
    __shared__ float hrow[128];
    int g = blockIdx.x;
    int cp = threadIdx.x & 63;
    int j = threadIdx.x >> 6;  // 0..15
    int s = goffs[g], e = goffs[g + 1];
    float a0 = 0.f, a1 = 0.f;
    for (int r = s + j; r < e; r += 16) {
        uint32 u = x2b[(size_t)r * 64 + cp];
        a0 += bflo(u); a1 += bfhi(u);
    }
    red[j][cp * 2] = a0;
    red[j][cp * 2 + 1] = a1;
    __syncthreads();
    if (j == 0) {
        float t0 = 0.f, t1 = 0.f;
#pragma unroll
        for (int jj = 0; jj < 16; jj++) { t0 += red[jj][cp * 2]; t1 += red[jj][cp * 2 + 1]; }
        float cnt = fmaxf((float)(e - s), 1.0f);
        hrow[cp * 2] = t0 / cnt;
        hrow[cp * 2 + 1] = t1 / cnt;
    }
    __syncthreads();
    if (threadIdx.x < 10) {
        int c = threadIdx.x;
        float acc = bc[c];
#pragma unroll 8
        for (int k = 0; k < 128; k++) acc = fmaf(hrow[k], Wc[k * 10 + c], acc);
        const float* prow = perm + g * 64;
#pragma unroll 8
        for (int p = 0; p < 64; p++) acc = fmaf(prow[p], Wc[(128 + p) * 10 + c], acc);
        out[g * 10 + c] = acc;
    }
}

extern "C" void kernel_launch(void* const* d_in, const int* in_sizes, int n_in,
                              void* d_out, int out_size, void* d_ws, size_t ws_size,
                              hipStream_t stream) {
    const float* h    = (const float*)d_in[0];
    const float* perm = (const float*)d_in[1];
    const float* W1   = (const float*)d_in[2];
    const float* b1   = (const float*)d_in[3];
    const float* W2   = (const float*)d_in[4];
    const float* b2   = (const float*)d_in[5];
    const float* Wc   = (const float*)d_in[6];
    const float* bc   = (const float*)d_in[7];
    const int* src    = (const int*)d_in[8];
    const int* dst    = (const int*)d_in[9];
    const int* gids   = (const int*)d_in[10];
    float* out = (float*)d_out;

    const int N = in_sizes[0] / 128;
    const int E = in_sizes[8];
    const int G = NUM_G, H = 128;
    const int B = (E + PB_EDGES - 1) / PB_EDGES;
    const int NBIN = (N + W_BIN - 1) / W_BIN;

    char* w = (char*)d_ws;
    size_t off = 0;
    auto alloc = [&](size_t bytes) -> void* {
        void* p = w + off;
        off = (off + bytes + 255) & ~(size_t)255;
        return p;
    };
    uint32* xsb   = (uint32*)alloc((size_t)N * H * 2);  // chunked bf16 in; later x2 row-major
    uint32* aggb  = (uint32*)alloc((size_t)N * H * 2);  // chunked bf16 agg out
    uint32* x1b   = (uint32*)alloc((size_t)N * H * 2);  // chunked bf16 layer-1 out
    unsigned short* Wt1 = (unsigned short*)alloc(16384 * 2);
    unsigned short* Wt2 = (unsigned short*)alloc(16384 * 2);
    int*    adj     = (int*)alloc((size_t)E * 4);
    int*    coff    = (int*)alloc((size_t)(N + 1) * 4);
    int*    indeg   = (int*)alloc((size_t)N * 4);
    int*    outdeg  = (int*)alloc((size_t)N * 4);
    float*  nrm_out = (float*)alloc((size_t)N * 4);
    float*  nrm_in  = (float*)alloc((size_t)N * 4);
    int*    goffs   = (int*)alloc((size_t)(G + 1) * 4);

    // Build temporaries alias aggb (dead until agg_kernel writes it).
    char* tmp = (char*)aggb;
    size_t toff = 0;
    auto talloc = [&](size_t bytes) -> void* {
        void* p = tmp + toff;
        toff = (toff + bytes + 255) & ~(size_t)255;
        return p;
    };
    int2* ebuf   = (int2*)talloc((size_t)E * 8);
    int*  sbuf   = (int*)talloc((size_t)E * 4);
    int*  bh     = (int*)talloc((size_t)2 * B * NBIN * 4);
    int*  curs   = (int*)talloc((size_t)2 * B * NBIN * 4);
    int*  tot    = (int*)talloc((size_t)2 * NBIN * 4);
    int*  bstart = (int*)talloc((size_t)2 * (NBIN + 1) * 4);

    // ---- atomic-free graph build ----
    p1_hist<<<2 * B, 256, 0, stream>>>(src, dst, E, NBIN, B, bh);
    p2a_tot<<<2 * NBIN, 256, 0, stream>>>(bh, NBIN, B, tot);
    p2c_cursor<<<2 * NBIN, 512, 0, stream>>>(bh, tot, NBIN, B, E, bstart, curs);
    p3_scatter<<<2 * B, 256, 0, stream>>>(src, dst, E, NBIN, B, curs, ebuf, sbuf);
    p4_comb<<<2 * NBIN, 256, 0, stream>>>(ebuf, sbuf, bstart, NBIN, N, E,
                                          indeg, coff, adj, outdeg);

    misc_kernel<<<(N + 1 + 255) / 256, 256, 0, stream>>>(gids, outdeg, indeg, W1, W2, N,
                                                         goffs, nrm_out, nrm_in, Wt1, Wt2);

    const int NG8 = 8 * ((N + 127) / 128);

    // layer 1
    scale_kernel<<<NG8, 256, 0, stream>>>(h, nrm_out, xsb, N);
    agg_kernel<<<NG8, 256, 0, stream>>>(xsb, adj, coff, aggb, N);
    gemm_mfma<true><<<(N + 127) / 128, 256, 0, stream>>>((const unsigned short*)aggb, Wt1, b1,
                                                         nrm_in, nrm_out,
                                                         (unsigned short*)x1b, N, 1);

    // layer 2 (row-major bf16 out into xsb, dead after agg1)
    agg_kernel<<<NG8, 256, 0, stream>>>(x1b, adj, coff, aggb, N);
    gemm_mfma<false><<<(N + 127) / 128, 256, 0, stream>>>((const unsigned short*)aggb, Wt2, b2,
                                                          nrm_in, nullptr,
                                                          (unsigned short*)xsb, N, 0);

    // fused readout
    mean_final<<<G, 1024, 0, stream>>>(xsb, goffs, perm, Wc, bc, out);
}

// Round 10
// 353.086 us; speedup vs baseline: 1.2521x; 1.2521x over previous
//
#include <hip/hip_runtime.h>

// GCN: 2x GraphConv(norm='both') + per-graph mean + [hg|perm] @ Wc + bc
// N=100000, E=1600000, D=H=128, P=64, C=10, G=128
// R10: revert R9's chunked layout (50% line util + fragmented gathers -> 2.0TB/s).
// R8 row-major structure + agg unroll-8 + packed int32 edge buffer.

#define NUM_G 128
#define PB_EDGES 4096   // edges per partition block
#define W_BIN 128       // nodes per bin (key>>7)

typedef unsigned int uint32;
typedef short bf16x8 __attribute__((ext_vector_type(8)));
typedef float f32x4 __attribute__((ext_vector_type(4)));

__device__ __forceinline__ float bflo(uint32 u) { return __uint_as_float(u << 16); }
__device__ __forceinline__ float bfhi(uint32 u) { return __uint_as_float(u & 0xffff0000u); }
__device__ __forceinline__ uint32 f2bf_bits(float f) {  // RNE
    uint32 b = __float_as_uint(f);
    return (b + 0x7fffu + ((b >> 16) & 1u)) >> 16;
}
__device__ __forceinline__ uint32 pack2(float a, float b) {
    return f2bf_bits(a) | (f2bf_bits(b) << 16);
}

// ---- P1: per-block LDS histogram of key>>7. pipe0=dst, pipe1=src ----
__global__ __launch_bounds__(256) void p1_hist(const int* __restrict__ src,
                                               const int* __restrict__ dst, int E,
                                               int NBIN, int B, int* __restrict__ bh) {
    __shared__ int hist[1024];
    int b = blockIdx.x;
    int pipe = (b >= B) ? 1 : 0;
    int bb = pipe ? b - B : b;
    const int* key = pipe ? src : dst;
    for (int i = threadIdx.x; i < NBIN; i += 256) hist[i] = 0;
    __syncthreads();
    int base = bb * PB_EDGES;
    for (int c = threadIdx.x; c < PB_EDGES / 4; c += 256) {
        int e = base + c * 4;
        if (e + 3 < E) {
            int4 k4 = *(const int4*)(key + e);
            atomicAdd(&hist[k4.x >> 7], 1);
            atomicAdd(&hist[k4.y >> 7], 1);
            atomicAdd(&hist[k4.z >> 7], 1);
            atomicAdd(&hist[k4.w >> 7], 1);
        } else {
            for (int i = e; i < E && i < e + 4; i++) atomicAdd(&hist[key[i] >> 7], 1);
        }
    }
    __syncthreads();
    int* outp = bh + (size_t)pipe * NBIN * B;
    for (int k = threadIdx.x; k < NBIN; k += 256)
        outp[(size_t)k * B + bb] = hist[k];
}

// ---- P2a: tot[pipe][k] = sum_b bh[pipe][k][b] ----
__global__ __launch_bounds__(256) void p2a_tot(const int* __restrict__ bh, int NBIN, int B,
                                               int* __restrict__ tot) {
    __shared__ int sc[256];
    int k = blockIdx.x % NBIN, pipe = blockIdx.x / NBIN;
    const int* row = bh + (size_t)pipe * NBIN * B + (size_t)k * B;
    int acc = 0;
    for (int b = threadIdx.x; b < B; b += 256) acc += row[b];
    sc[threadIdx.x] = acc;
    __syncthreads();
    for (int o = 128; o > 0; o >>= 1) {
        if (threadIdx.x < o) sc[threadIdx.x] += sc[threadIdx.x + o];
        __syncthreads();
    }
    if (threadIdx.x == 0) tot[pipe * NBIN + k] = sc[0];
}

// ---- P2c: block (pipe,k): base = prefix(tot) inline; write bstart; scan bh over B ----
__global__ __launch_bounds__(512) void p2c_cursor(const int* __restrict__ bh,
                                                  const int* __restrict__ tot,
                                                  int NBIN, int B, int E,
                                                  int* __restrict__ bstart,
                                                  int* __restrict__ curs) {
    __shared__ int sc[512];
    int k = blockIdx.x % NBIN, pipe = blockIdx.x / NBIN;
    int i = threadIdx.x;
    int pacc = 0;
    for (int kk = i; kk < k; kk += 512) pacc += tot[pipe * NBIN + kk];
    sc[i] = pacc;
    __syncthreads();
    for (int o = 256; o > 0; o >>= 1) {
        if (i < o) sc[i] += sc[i + o];
        __syncthreads();
    }
    int base = sc[0];
    __syncthreads();
    if (i == 0) {
        bstart[pipe * (NBIN + 1) + k] = base;
        if (k == 0) bstart[pipe * (NBIN + 1) + NBIN] = E;
    }
    const int* row = bh + (size_t)pipe * NBIN * B + (size_t)k * B;
    int v = (i < B) ? row[i] : 0;
    sc[i] = v;
    __syncthreads();
    for (int o = 1; o < 512; o <<= 1) {
        int t = (i >= o) ? sc[i - o] : 0;
        __syncthreads();
        sc[i] += t;
        __syncthreads();
    }
    if (i < B)
        curs[(size_t)pipe * B * NBIN + (size_t)i * NBIN + k] = base + sc[i] - v;
}

// ---- P3: scatter edges into bin-partitioned buffers (LDS cursors) ----
// pipe0 entry: src | (dst&127)<<17  (src < 2^17; dst low bits for in-bin CSR)
__global__ __launch_bounds__(256) void p3_scatter(const int* __restrict__ src,
                                                  const int* __restrict__ dst, int E,
                                                  int NBIN, int B, const int* __restrict__ curs,
                                                  int* __restrict__ ebuf, int* __restrict__ sbuf) {
    __shared__ int cur[1024];
    int b = blockIdx.x;
    int pipe = (b >= B) ? 1 : 0;
    int bb = pipe ? b - B : b;
    const int* crow = curs + (size_t)pipe * B * NBIN + (size_t)bb * NBIN;
    for (int i = threadIdx.x; i < NBIN; i += 256) cur[i] = crow[i];
    __syncthreads();
    int base = bb * PB_EDGES;
    if (!pipe) {
        for (int c = threadIdx.x; c < PB_EDGES / 4; c += 256) {
            int e = base + c * 4;
            if (e + 3 < E) {
                int4 s4 = *(const int4*)(src + e);
                int4 d4 = *(const int4*)(dst + e);
                int p;
                p = atomicAdd(&cur[d4.x >> 7], 1); ebuf[p] = s4.x | ((d4.x & 127) << 17);
                p = atomicAdd(&cur[d4.y >> 7], 1); ebuf[p] = s4.y | ((d4.y & 127) << 17);
                p = atomicAdd(&cur[d4.z >> 7], 1); ebuf[p] = s4.z | ((d4.z & 127) << 17);
                p = atomicAdd(&cur[d4.w >> 7], 1); ebuf[p] = s4.w | ((d4.w & 127) << 17);
            } else {
                for (int i = e; i < E && i < e + 4; i++) {
                    int s = src[i], d = dst[i];
                    int p = atomicAdd(&cur[d >> 7], 1);
                    ebuf[p] = s | ((d & 127) << 17);
                }
            }
        }
    } else {
        for (int c = threadIdx.x; c < PB_EDGES / 4; c += 256) {
            int e = base + c * 4;
            if (e + 3 < E) {
                int4 s4 = *(const int4*)(src + e);
                int p;
                p = atomicAdd(&cur[s4.x >> 7], 1); sbuf[p] = s4.x;
                p = atomicAdd(&cur[s4.y >> 7], 1); sbuf[p] = s4.y;
                p = atomicAdd(&cur[s4.z >> 7], 1); sbuf[p] = s4.z;
                p = atomicAdd(&cur[s4.w >> 7], 1); sbuf[p] = s4.w;
            } else {
                for (int i = e; i < E && i < e + 4; i++) {
                    int s = src[i];
                    int p = atomicAdd(&cur[s >> 7], 1);
                    sbuf[p] = s;
                }
            }
        }
    }
}

// ---- P4 (fused): k<NBIN: per-bin CSR from packed ebuf; k>=NBIN: per-bin outdeg ----
__global__ __launch_bounds__(256) void p4_comb(const int* __restrict__ ebuf,
                                               const int* __restrict__ sbuf,
                                               const int* __restrict__ bstart,
                                               int NBIN, int N, int E,
                                               int* __restrict__ indeg, int* __restrict__ coff,
                                               int* __restrict__ adj, int* __restrict__ outdeg) {
    __shared__ int hist[128];
    __shared__ int sc[128];
    __shared__ int cur[128];
    __shared__ int lsrc[4096];
    int kb = blockIdx.x;
    int tid = threadIdx.x;
    if (kb >= NBIN) {
        int k = kb - NBIN;
        const int* bstartS = bstart + (NBIN + 1);
        int s0 = bstartS[k], s1 = bstartS[k + 1];
        if (tid < 128) hist[tid] = 0;
        __syncthreads();
        for (int i = s0 + tid; i < s1; i += 256) atomicAdd(&hist[sbuf[i] & 127], 1);
        __syncthreads();
        if (tid < 128) {
            int node = k * W_BIN + tid;
            if (node < N) outdeg[node] = hist[tid];
        }
        return;
    }
    int k = kb;
    int s0 = bstart[k], s1 = bstart[k + 1];
    int M = s1 - s0;
    if (tid < 128) hist[tid] = 0;
    __syncthreads();
    for (int i = tid; i < M; i += 256) {
        int e = ebuf[s0 + i];
        atomicAdd(&hist[(e >> 17) & 127], 1);
    }
    __syncthreads();
    if (tid < 128) sc[tid] = hist[tid];
    __syncthreads();
    for (int o = 1; o < 128; o <<= 1) {
        int v = 0;
        if (tid < 128 && tid >= o) v = sc[tid - o];
        __syncthreads();
        if (tid < 128) sc[tid] += v;
        __syncthreads();
    }
    if (tid < 128) {
        int node = k * W_BIN + tid;
        if (node < N) {
            indeg[node] = hist[tid];
            coff[node] = s0 + sc[tid] - hist[tid];
        }
        cur[tid] = sc[tid] - hist[tid];
    }
    if (k == NBIN - 1 && tid == 0) coff[N] = E;
    __syncthreads();
    if (M <= 4096) {
        for (int i = tid; i < M; i += 256) {
            int e = ebuf[s0 + i];
            int p = atomicAdd(&cur[(e >> 17) & 127], 1);
            lsrc[p] = e & 0x1FFFF;
        }
        __syncthreads();
        for (int i = tid; i < M; i += 256) adj[s0 + i] = lsrc[i];
    } else {
        for (int i = tid; i < M; i += 256) {
            int e = ebuf[s0 + i];
            int p = atomicAdd(&cur[(e >> 17) & 127], 1);
            adj[s0 + p] = e & 0x1FFFF;
        }
    }
}

// ---- misc (fused): goffs boundary-detect + degree norms + Wt bf16 transpose ----
__global__ void misc_kernel(const int* __restrict__ gids,
                            const int* __restrict__ outdeg, const int* __restrict__ indeg,
                            const float* __restrict__ W1, const float* __restrict__ W2,
                            int N, int* __restrict__ goffs,
                            float* __restrict__ nrm_out, float* __restrict__ nrm_in,
                            unsigned short* __restrict__ Wt1, unsigned short* __restrict__ Wt2) {
    int i = blockIdx.x * blockDim.x + threadIdx.x;
    if (i <= N) {
        int prev = (i == 0) ? -1 : gids[i - 1];
        int cur = (i == N) ? NUM_G : gids[i];
        for (int g = prev + 1; g <= cur && g <= NUM_G; g++) goffs[g] = i;
    }
    if (i < N) {
        nrm_out[i] = rsqrtf(fmaxf((float)outdeg[i], 1.0f));
        nrm_in[i]  = rsqrtf(fmaxf((float)indeg[i], 1.0f));
    }
    if (i < 32768) {
        int sel = i >> 14;
        int idx = i & 16383;
        int k = idx >> 7, n = idx & 127;
        float v = (sel ? W2 : W1)[idx];
        (sel ? Wt2 : Wt1)[n * 128 + k] = (unsigned short)f2bf_bits(v);
    }
}

// ---- xsb[n] = bf16(h[n] * nrm_out[n]) : 16 lanes/node, 8 elems/lane ----
__global__ void scale_kernel(const float* __restrict__ h, const float* __restrict__ nrm_out,
                             uint32* __restrict__ xsb, int N) {
    int t = blockIdx.x * blockDim.x + threadIdx.x;
    int node = t >> 4, q = t & 15;
    if (node >= N) return;
    float ns = nrm_out[node];
    const float4* hv = (const float4*)(h + (size_t)node * 128 + q * 8);
    float4 a = hv[0], b = hv[1];
    a.x *= ns; a.y *= ns; a.z *= ns; a.w *= ns;
    b.x *= ns; b.y *= ns; b.z *= ns; b.w *= ns;
    uint4 o;
    o.x = pack2(a.x, a.y); o.y = pack2(a.z, a.w);
    o.z = pack2(b.x, b.y); o.w = pack2(b.z, b.w);
    ((uint4*)xsb)[(size_t)node * 16 + q] = o;
}

__device__ __forceinline__ void acc8(float* acc, uint4 u) {
    acc[0] += bflo(u.x); acc[1] += bfhi(u.x); acc[2] += bflo(u.y); acc[3] += bfhi(u.y);
    acc[4] += bflo(u.z); acc[5] += bfhi(u.z); acc[6] += bflo(u.w); acc[7] += bfhi(u.w);
}

// ---- aggregation: 16 lanes/node, row-major 256B rows, unroll-8 MLP ----
__global__ void agg_kernel(const uint32* __restrict__ xsb, const int* __restrict__ adj,
                           const int* __restrict__ coff, uint32* __restrict__ aggb, int N) {
    int t = blockIdx.x * blockDim.x + threadIdx.x;
    int node = t >> 4;
    int q = t & 15;
    if (node >= N) return;
    int jb = coff[node], je = coff[node + 1];
    float acc[8];
#pragma unroll
    for (int i = 0; i < 8; i++) acc[i] = 0.f;
    const uint4* rows = (const uint4*)xsb;
    int j = jb;
    for (; j + 7 < je; j += 8) {
        int s0 = adj[j], s1 = adj[j + 1], s2 = adj[j + 2], s3 = adj[j + 3];
        int s4 = adj[j + 4], s5 = adj[j + 5], s6 = adj[j + 6], s7 = adj[j + 7];
        uint4 u0 = rows[(size_t)s0 * 16 + q];
        uint4 u1 = rows[(size_t)s1 * 16 + q];
        uint4 u2 = rows[(size_t)s2 * 16 + q];
        uint4 u3 = rows[(size_t)s3 * 16 + q];
        uint4 u4 = rows[(size_t)s4 * 16 + q];
        uint4 u5 = rows[(size_t)s5 * 16 + q];
        uint4 u6 = rows[(size_t)s6 * 16 + q];
        uint4 u7 = rows[(size_t)s7 * 16 + q];
        acc8(acc, u0); acc8(acc, u1); acc8(acc, u2); acc8(acc, u3);
        acc8(acc, u4); acc8(acc, u5); acc8(acc, u6); acc8(acc, u7);
    }
    for (; j + 3 < je; j += 4) {
        int s0 = adj[j], s1 = adj[j + 1], s2 = adj[j + 2], s3 = adj[j + 3];
        uint4 u0 = rows[(size_t)s0 * 16 + q];
        uint4 u1 = rows[(size_t)s1 * 16 + q];
        uint4 u2 = rows[(size_t)s2 * 16 + q];
        uint4 u3 = rows[(size_t)s3 * 16 + q];
        acc8(acc, u0); acc8(acc, u1); acc8(acc, u2); acc8(acc, u3);
    }
    for (; j < je; j++) {
        uint4 u = rows[(size_t)adj[j] * 16 + q];
        acc8(acc, u);
    }
    uint4 o;
    o.x = pack2(acc[0], acc[1]); o.y = pack2(acc[2], acc[3]);
    o.z = pack2(acc[4], acc[5]); o.w = pack2(acc[6], acc[7]);
    ((uint4*)aggb)[(size_t)node * 16 + q] = o;
}

// ---- MFMA GEMM: 4 waves x 32 rows = 128 rows/block; B-frag shared by 2 row-tiles ----
__global__ __launch_bounds__(256) void gemm_mfma(const unsigned short* __restrict__ A,
                                                 const unsigned short* __restrict__ Wtg,
                                                 const float* __restrict__ bias,
                                                 const float* __restrict__ rowscale,
                                                 const float* __restrict__ postscale,
                                                 unsigned short* __restrict__ out,
                                                 int N, int do_relu) {
    __shared__ unsigned short Wl[128 * 136];
    for (int i = threadIdx.x; i < 2048; i += 256) {
        uint4 v = ((const uint4*)Wtg)[i];
        *(uint4*)&Wl[(i >> 4) * 136 + (i & 15) * 8] = v;
    }
    __syncthreads();

    int lane = threadIdx.x & 63;
    int wv = threadIdx.x >> 6;
    int col_l = lane & 15;
    int quad = lane >> 4;
    int r0w = blockIdx.x * 128 + wv * 32;
    if (r0w >= N) return;

    int arow0 = r0w + col_l;        if (arow0 >= N) arow0 = N - 1;
    int arow1 = r0w + 16 + col_l;   if (arow1 >= N) arow1 = N - 1;
    const unsigned short* Ar0 = A + (size_t)arow0 * 128;
    const unsigned short* Ar1 = A + (size_t)arow1 * 128;

    f32x4 acc[2][8];
#pragma unroll
    for (int rt = 0; rt < 2; rt++)
#pragma unroll
        for (int t = 0; t < 8; t++) {
            acc[rt][t][0] = 0.f; acc[rt][t][1] = 0.f;
            acc[rt][t][2] = 0.f; acc[rt][t][3] = 0.f;
        }

#pragma unroll
    for (int kk = 0; kk < 4; kk++) {
        bf16x8 a0 = *(const bf16x8*)(Ar0 + kk * 32 + quad * 8);
        bf16x8 a1 = *(const bf16x8*)(Ar1 + kk * 32 + quad * 8);
        const unsigned short* wb = &Wl[(size_t)col_l * 136 + kk * 32 + quad * 8];
#pragma unroll
        for (int t = 0; t < 8; t++) {
            bf16x8 b = *(const bf16x8*)(wb + (size_t)t * 16 * 136);
            acc[0][t] = __builtin_amdgcn_mfma_f32_16x16x32_bf16(a0, b, acc[0][t], 0, 0, 0);
            acc[1][t] = __builtin_amdgcn_mfma_f32_16x16x32_bf16(a1, b, acc[1][t], 0, 0, 0);
        }
    }

#pragma unroll
    for (int rt = 0; rt < 2; rt++) {
        int rbase = r0w + rt * 16;
        float s[4], p[4];
#pragma unroll
        for (int j = 0; j < 4; j++) {
            int rw = rbase + quad * 4 + j;
            bool ok = rw < N;
            s[j] = ok ? rowscale[ok ? rw : 0] : 0.f;
            p[j] = (postscale != nullptr && ok) ? postscale[rw] : 1.f;
        }
#pragma unroll
        for (int t = 0; t < 8; t++) {
            int c = t * 16 + col_l;
            float bia = bias[c];
#pragma unroll
            for (int j = 0; j < 4; j++) {
                int rw = rbase + quad * 4 + j;
                if (rw >= N) continue;
                float v = fmaf(s[j], acc[rt][t][j], bia);
                if (do_relu) v = fmaxf(v, 0.f);
                v *= p[j];
                out[(size_t)rw * 128 + c] = (unsigned short)f2bf_bits(v);
            }
        }
    }
}

// ---- fused per-graph mean + classifier head ----
__global__ __launch_bounds__(1024) void mean_final(const uint32* __restrict__ x2b,
                                                   const int* __restrict__ goffs,
                                                   const float* __restrict__ perm,
                                                   const float* __restrict__ Wc,
                                                   const float* __restrict__ bc,
                                                   float* __restrict__ out) {
    __shared__ float red[16][128];
    __shared__ float hrow[128];
    int g = blockIdx.x;
    int cp = threadIdx.x & 63;
    int j = threadIdx.x >> 6;  // 0..15
    int s = goffs[g], e = goffs[g + 1];
    float a0 = 0.f, a1 = 0.f;
    for (int r = s + j; r < e; r += 16) {
        uint32 u = x2b[(size_t)r * 64 + cp];
        a0 += bflo(u); a1 += bfhi(u);
    }
    red[j][cp * 2] = a0;
    red[j][cp * 2 + 1] = a1;
    __syncthreads();
    if (j == 0) {
        float t0 = 0.f, t1 = 0.f;
#pragma unroll
        for (int jj = 0; jj < 16; jj++) { t0 += red[jj][cp * 2]; t1 += red[jj][cp * 2 + 1]; }
        float cnt = fmaxf((float)(e - s), 1.0f);
        hrow[cp * 2] = t0 / cnt;
        hrow[cp * 2 + 1] = t1 / cnt;
    }
    __syncthreads();
    if (threadIdx.x < 10) {
        int c = threadIdx.x;
        float acc = bc[c];
#pragma unroll 8
        for (int k = 0; k < 128; k++) acc = fmaf(hrow[k], Wc[k * 10 + c], acc);
        const float* prow = perm + g * 64;
#pragma unroll 8
        for (int p = 0; p < 64; p++) acc = fmaf(prow[p], Wc[(128 + p) * 10 + c], acc);
        out[g * 10 + c] = acc;
    }
}

extern "C" void kernel_launch(void* const* d_in, const int* in_sizes, int n_in,
                              void* d_out, int out_size, void* d_ws, size_t ws_size,
                              hipStream_t stream) {
    const float* h    = (const float*)d_in[0];
    const float* perm = (const float*)d_in[1];
    const float* W1   = (const float*)d_in[2];
    const float* b1   = (const float*)d_in[3];
    const float* W2   = (const float*)d_in[4];
    const float* b2   = (const float*)d_in[5];
    const float* Wc   = (const float*)d_in[6];
    const float* bc   = (const float*)d_in[7];
    const int* src    = (const int*)d_in[8];
    const int* dst    = (const int*)d_in[9];
    const int* gids   = (const int*)d_in[10];
    float* out = (float*)d_out;

    const int N = in_sizes[0] / 128;
    const int E = in_sizes[8];
    const int G = NUM_G, H = 128;
    const int B = (E + PB_EDGES - 1) / PB_EDGES;
    const int NBIN = (N + W_BIN - 1) / W_BIN;

    char* w = (char*)d_ws;
    size_t off = 0;
    auto alloc = [&](size_t bytes) -> void* {
        void* p = w + off;
        off = (off + bytes + 255) & ~(size_t)255;
        return p;
    };
    uint32* xsb   = (uint32*)alloc((size_t)N * H * 2);  // bf16 scaled in; later x2 out
    uint32* aggb  = (uint32*)alloc((size_t)N * H * 2);  // bf16 agg out (both layers)
    uint32* x1b   = (uint32*)alloc((size_t)N * H * 2);  // bf16 layer-1 out
    unsigned short* Wt1 = (unsigned short*)alloc(16384 * 2);
    unsigned short* Wt2 = (unsigned short*)alloc(16384 * 2);
    int*    adj     = (int*)alloc((size_t)E * 4);
    int*    coff    = (int*)alloc((size_t)(N + 1) * 4);
    int*    indeg   = (int*)alloc((size_t)N * 4);
    int*    outdeg  = (int*)alloc((size_t)N * 4);
    float*  nrm_out = (float*)alloc((size_t)N * 4);
    float*  nrm_in  = (float*)alloc((size_t)N * 4);
    int*    goffs   = (int*)alloc((size_t)(G + 1) * 4);

    // Build temporaries alias aggb (dead until agg_kernel writes it).
    char* tmp = (char*)aggb;
    size_t toff = 0;
    auto talloc = [&](size_t bytes) -> void* {
        void* p = tmp + toff;
        toff = (toff + bytes + 255) & ~(size_t)255;
        return p;
    };
    int*  ebuf   = (int*)talloc((size_t)E * 4);   // packed src | dstlow<<17
    int*  sbuf   = (int*)talloc((size_t)E * 4);
    int*  bh     = (int*)talloc((size_t)2 * B * NBIN * 4);
    int*  curs   = (int*)talloc((size_t)2 * B * NBIN * 4);
    int*  tot    = (int*)talloc((size_t)2 * NBIN * 4);
    int*  bstart = (int*)talloc((size_t)2 * (NBIN + 1) * 4);

    // ---- atomic-free graph build ----
    p1_hist<<<2 * B, 256, 0, stream>>>(src, dst, E, NBIN, B, bh);
    p2a_tot<<<2 * NBIN, 256, 0, stream>>>(bh, NBIN, B, tot);
    p2c_cursor<<<2 * NBIN, 512, 0, stream>>>(bh, tot, NBIN, B, E, bstart, curs);
    p3_scatter<<<2 * B, 256, 0, stream>>>(src, dst, E, NBIN, B, curs, ebuf, sbuf);
    p4_comb<<<2 * NBIN, 256, 0, stream>>>(ebuf, sbuf, bstart, NBIN, N, E,
                                          indeg, coff, adj, outdeg);

    misc_kernel<<<(N + 1 + 255) / 256, 256, 0, stream>>>(gids, outdeg, indeg, W1, W2, N,
                                                         goffs, nrm_out, nrm_in, Wt1, Wt2);

    // layer 1
    scale_kernel<<<(N * 16 + 255) / 256, 256, 0, stream>>>(h, nrm_out, xsb, N);
    agg_kernel<<<(N * 16 + 255) / 256, 256, 0, stream>>>(xsb, adj, coff, aggb, N);
    gemm_mfma<<<(N + 127) / 128, 256, 0, stream>>>((const unsigned short*)aggb, Wt1, b1,
                                                   nrm_in, nrm_out,
                                                   (unsigned short*)x1b, N, 1);

    // layer 2 (output bf16 into xsb, dead after agg1)
    agg_kernel<<<(N * 16 + 255) / 256, 256, 0, stream>>>(x1b, adj, coff, aggb, N);
    gemm_mfma<<<(N + 127) / 128, 256, 0, stream>>>((const unsigned short*)aggb, Wt2, b2,
                                                   nrm_in, nullptr,
                                                   (unsigned short*)xsb, N, 0);

    // fused readout
    mean_final<<<G, 1024, 0, stream>>>(xsb, goffs, perm, Wc, bc, out);
}